// Round 2
// baseline (909.091 us; speedup 1.0000x reference)
//
#include <hip/hip_runtime.h>
#include <hip/hip_bf16.h>

#define DEV __device__ __forceinline__

typedef __bf16 bf16x8 __attribute__((ext_vector_type(8)));
typedef float f32x4 __attribute__((ext_vector_type(4)));
typedef short s16x8 __attribute__((ext_vector_type(8)));
typedef unsigned short u16;

static constexpr int D = 1024;
static constexpr int M = 8 * 2048;   // 16384 rows
static constexpr float EPS = 1e-8f;

DEV u16 f2bf(float f) {
  union { float f; unsigned u; } v; v.f = f;
  unsigned u = v.u;
  return (u16)((u + 0x7FFFu + ((u >> 16) & 1u)) >> 16);  // RNE
}
DEV float bf2f(u16 h) {
  union { unsigned u; float f; } v; v.u = ((unsigned)h) << 16;
  return v.f;
}

// Shared unit-index scheme for ALL LDS tiles (A and B, hi and lo):
// unit(row, kg) holds k = k0 + kg*8 .. +8 of `row`; 16B per unit.
// Using ONE function for every store and every fragment read guarantees any
// lane->k map error cancels between A and B.
DEV int unit_of(int row, int kg) { return ((row >> 4) * 4 + kg) * 16 + (row & 15); }

// ---------------- K1: per-row coherence -> scale ----------------
// cos(atan2(y,x)) = x/r, sin = y/r; coherence = (sc^2+ss^2)/D^2
__global__ __launch_bounds__(256) void k_coherence(const float* __restrict__ xr,
                                                   const float* __restrict__ xi,
                                                   const float* __restrict__ cfp,
                                                   float* __restrict__ scale) {
  int row = blockIdx.x;
  int tid = threadIdx.x;
  float4 r4 = ((const float4*)(xr + (size_t)row * D))[tid];
  float4 i4 = ((const float4*)(xi + (size_t)row * D))[tid];
  float xs[4] = {r4.x, r4.y, r4.z, r4.w};
  float ys[4] = {i4.x, i4.y, i4.z, i4.w};
  float sc = 0.f, ss = 0.f;
#pragma unroll
  for (int j = 0; j < 4; ++j) {
    float x = xs[j] + EPS, y = ys[j] + EPS;
    float inv = rsqrtf(x * x + y * y);
    sc += x * inv;
    ss += y * inv;
  }
#pragma unroll
  for (int off = 32; off > 0; off >>= 1) {
    sc += __shfl_down(sc, off, 64);
    ss += __shfl_down(ss, off, 64);
  }
  __shared__ float red[8];
  int wid = tid >> 6, lane = tid & 63;
  if (lane == 0) { red[wid] = sc; red[wid + 4] = ss; }
  __syncthreads();
  if (tid == 0) {
    float tsc = red[0] + red[1] + red[2] + red[3];
    float tss = red[4] + red[5] + red[6] + red[7];
    float coh = (tsc * tsc + tss * tss) * (1.0f / ((float)D * (float)D));
    scale[row] = cfp[0] * (1.0f - coh);
  }
}

// ---------------- K2: split-bf16 MFMA GEMM + fused rotation epilogue ----------------
// pa = x_real @ phase_matrix computed as Ah*Bh + Ah*Bl + Al*Bh (hi/lo bf16 split)
// -> rounding error ~1e-5, removes bf16 precision as a failure hypothesis.
// B is staged straight from pm (f32 [k][n], coalesced loads, scattered ds_write)
// -> no k_transpose, no global_load_lds, no bt workspace.
__global__ __launch_bounds__(256) void k_gemm(const float* __restrict__ xr,
                                              const float* __restrict__ xi,
                                              const float* __restrict__ pm,
                                              const float* __restrict__ scale,
                                              float* __restrict__ outR,
                                              float* __restrict__ outI) {
  __shared__ __align__(16) u16 As_h[4096];  // 128 rows x 32 k, fragment-major
  __shared__ __align__(16) u16 As_l[4096];
  __shared__ __align__(16) u16 Bs_h[4096];  // 128 cols x 32 k, fragment-major
  __shared__ __align__(16) u16 Bs_l[4096];

  const int tid = threadIdx.x;
  const int lane = tid & 63;
  const int wid = tid >> 6;
  const int wr = wid >> 1, wc = wid & 1;
  const int tn = blockIdx.x & 7;   // 8 N-tiles
  const int tm = blockIdx.x >> 3;  // 128 M-tiles
  const int l15 = lane & 15, l4 = lane >> 4;

  f32x4 acc[4][4] = {};

  for (int kk = 0; kk < D / 32; ++kk) {
    const int k0 = kk * 32;

    // ---- stage A (hi+lo): 2 units/thread, vectorized 16B LDS writes ----
#pragma unroll
    for (int r = 0; r < 2; ++r) {
      int idx = r * 256 + tid;
      int row = idx >> 2, kg = idx & 3;
      const float* src = xr + (size_t)(tm * 128 + row) * D + k0 + kg * 8;
      float4 a = ((const float4*)src)[0];
      float4 b = ((const float4*)src)[1];
      float fv[8] = {a.x, a.y, a.z, a.w, b.x, b.y, b.z, b.w};
      s16x8 vh, vl;
#pragma unroll
      for (int j = 0; j < 8; ++j) {
        u16 h = f2bf(fv[j]);
        vh[j] = (short)h;
        vl[j] = (short)f2bf(fv[j] - bf2f(h));
      }
      int u = unit_of(row, kg);
      *(s16x8*)&As_h[u * 8] = vh;
      *(s16x8*)&As_l[u * 8] = vl;
    }

    // ---- stage B (hi+lo) from pm[k][n]: coalesced loads, scalar ds_writes ----
    {
      int kr = tid >> 3;   // 0..31 (k within tile)
      int ng = tid & 7;    // 0..7  (16-col group)
      const float* src = pm + (size_t)(k0 + kr) * D + tn * 128 + ng * 16;
      int kg = kr >> 3, j = kr & 7;
#pragma unroll
      for (int q = 0; q < 4; ++q) {
        float4 f4 = ((const float4*)src)[q];
        float fv[4] = {f4.x, f4.y, f4.z, f4.w};
#pragma unroll
        for (int c4 = 0; c4 < 4; ++c4) {
          int c = q * 4 + c4;               // col within group
          int u = unit_of(ng * 16 + c, kg); // same scheme as A
          u16 h = f2bf(fv[c4]);
          Bs_h[u * 8 + j] = h;
          Bs_l[u * 8 + j] = f2bf(fv[c4] - bf2f(h));
        }
      }
    }
    __syncthreads();

    bf16x8 ah[4], al[4], bh[4], bl[4];
#pragma unroll
    for (int mf = 0; mf < 4; ++mf) {
      int u = unit_of((wr * 4 + mf) * 16 + l15, l4);
      ah[mf] = __builtin_bit_cast(bf16x8, *(const s16x8*)&As_h[u * 8]);
      al[mf] = __builtin_bit_cast(bf16x8, *(const s16x8*)&As_l[u * 8]);
    }
#pragma unroll
    for (int nf = 0; nf < 4; ++nf) {
      int u = unit_of((wc * 4 + nf) * 16 + l15, l4);
      bh[nf] = __builtin_bit_cast(bf16x8, *(const s16x8*)&Bs_h[u * 8]);
      bl[nf] = __builtin_bit_cast(bf16x8, *(const s16x8*)&Bs_l[u * 8]);
    }
#pragma unroll
    for (int mf = 0; mf < 4; ++mf)
#pragma unroll
      for (int nf = 0; nf < 4; ++nf) {
        acc[mf][nf] = __builtin_amdgcn_mfma_f32_16x16x32_bf16(ah[mf], bh[nf], acc[mf][nf], 0, 0, 0);
        acc[mf][nf] = __builtin_amdgcn_mfma_f32_16x16x32_bf16(ah[mf], bl[nf], acc[mf][nf], 0, 0, 0);
        acc[mf][nf] = __builtin_amdgcn_mfma_f32_16x16x32_bf16(al[mf], bh[nf], acc[mf][nf], 0, 0, 0);
      }
    __syncthreads();
  }

  // epilogue: t = pa*scale -> rotate (x,y) by t -> unit-modulus normalize -> store
  // C/D layout (m89-verified): col = lane&15, row = (lane>>4)*4 + reg
#pragma unroll
  for (int mf = 0; mf < 4; ++mf) {
#pragma unroll
    for (int i = 0; i < 4; ++i) {
      int grow = tm * 128 + wr * 64 + mf * 16 + l4 * 4 + i;
      float scl = scale[grow];
      const float* xrp = xr + (size_t)grow * D;
      const float* xip = xi + (size_t)grow * D;
      float* orp = outR + (size_t)grow * D;
      float* oip = outI + (size_t)grow * D;
#pragma unroll
      for (int nf = 0; nf < 4; ++nf) {
        int gcol = tn * 128 + wc * 64 + nf * 16 + l15;
        float t = acc[mf][nf][i] * scl;
        float s = sinf(t), c = cosf(t);
        float a = xrp[gcol], b = xip[gcol];
        float nr = a * c - b * s;
        float ni = a * s + b * c;
        float inv = rsqrtf(nr * nr + ni * ni + EPS);
        orp[gcol] = nr * inv;
        oip[gcol] = ni * inv;
      }
    }
  }
}

// ---------------- K3: in-place LayerNorm over rows of d_out ----------------
__global__ __launch_bounds__(256) void k_layernorm(float* __restrict__ data,
                                                   const float* __restrict__ w,
                                                   const float* __restrict__ b) {
  size_t row = blockIdx.x;  // 0..2*M-1
  float* p = data + row * D;
  int tid = threadIdx.x;
  float4 v = ((const float4*)p)[tid];
  float s = v.x + v.y + v.z + v.w;
  float sq = v.x * v.x + v.y * v.y + v.z * v.z + v.w * v.w;
#pragma unroll
  for (int off = 32; off > 0; off >>= 1) {
    s += __shfl_down(s, off, 64);
    sq += __shfl_down(sq, off, 64);
  }
  __shared__ float red[8];
  __shared__ float stats[2];
  int wid = tid >> 6, lane = tid & 63;
  if (lane == 0) { red[wid] = s; red[wid + 4] = sq; }
  __syncthreads();
  if (tid == 0) {
    float ts = red[0] + red[1] + red[2] + red[3];
    float tq = red[4] + red[5] + red[6] + red[7];
    float mu = ts * (1.0f / D);
    float var = tq * (1.0f / D) - mu * mu;
    stats[0] = mu;
    stats[1] = rsqrtf(var + EPS);
  }
  __syncthreads();
  float mu = stats[0], rs = stats[1];
  float4 w4 = ((const float4*)w)[tid];
  float4 b4 = ((const float4*)b)[tid];
  float4 o;
  o.x = (v.x - mu) * rs * w4.x + b4.x;
  o.y = (v.y - mu) * rs * w4.y + b4.y;
  o.z = (v.z - mu) * rs * w4.z + b4.z;
  o.w = (v.w - mu) * rs * w4.w + b4.w;
  ((float4*)p)[tid] = o;
}

extern "C" void kernel_launch(void* const* d_in, const int* in_sizes, int n_in,
                              void* d_out, int out_size, void* d_ws, size_t ws_size,
                              hipStream_t stream) {
  const float* xr = (const float*)d_in[0];
  const float* xi = (const float*)d_in[1];
  const float* pm = (const float*)d_in[2];
  const float* cf = (const float*)d_in[3];
  const float* lw = (const float*)d_in[4];
  const float* lb = (const float*)d_in[5];
  float* outR = (float*)d_out;
  float* outI = outR + (size_t)M * D;
  float* scale = (float*)d_ws;  // 64 KB only

  k_coherence<<<M, 256, 0, stream>>>(xr, xi, cf, scale);
  k_gemm<<<(M / 128) * (D / 128), 256, 0, stream>>>(xr, xi, pm, scale, outR, outI);
  k_layernorm<<<2 * M, 256, 0, stream>>>((float*)d_out, lw, lb);
}

// Round 3
// 219.826 us; speedup vs baseline: 4.1355x; 4.1355x over previous
//
#include <hip/hip_runtime.h>

#define DEV __device__ __forceinline__

typedef __bf16 bf16x8 __attribute__((ext_vector_type(8)));
typedef float f32x4 __attribute__((ext_vector_type(4)));
typedef short s16x8 __attribute__((ext_vector_type(8)));
typedef unsigned short u16;

static constexpr int D = 1024;
static constexpr int M = 16384;   // 8*2048 rows
static constexpr int R = 64;      // rows per block
static constexpr float EPS = 1e-8f;

DEV u16 f2bf(float f) {
  union { float f; unsigned u; } v; v.f = f;
  unsigned u = v.u;
  return (u16)((u + 0x7FFFu + ((u >> 16) & 1u)) >> 16);  // RNE
}

// ---------------- prep: pm[k][n] f32 -> bt[n][k] bf16 ----------------
__global__ __launch_bounds__(256) void k_transpose(const float* __restrict__ pm,
                                                   u16* __restrict__ bt) {
  __shared__ float t[32][33];
  int bx = blockIdx.x * 32, by = blockIdx.y * 32;
  int tx = threadIdx.x, ty = threadIdx.y;  // 32 x 8
#pragma unroll
  for (int j = 0; j < 32; j += 8)
    t[ty + j][tx] = pm[(size_t)(by + ty + j) * D + bx + tx];
  __syncthreads();
#pragma unroll
  for (int j = 0; j < 32; j += 8)
    bt[(size_t)(bx + ty + j) * D + by + tx] = f2bf(t[tx][ty + j]);
}

// ---------------- fused: coherence + GEMM + rotation + LayerNorm ----------------
// One block per 64-row panel. A panel staged ONCE (128 KB LDS, fragment-major),
// B streamed from bf16 bt via double-buffered 8 KB tiles. All LDS accesses are
// b128 with lane-linear unit addresses (conflict-free by construction).
//
// Fragment convention (round-2-verified): a-frag row = base+l15, k-group = l4;
// b-frag col = base+l15, k-group = l4; C row = l4*4+reg, col = l15.
// A unit index: kk*256 + (row>>4)*64 + kgl*16 + (row&15)   (unit = 8 bf16 = 16B)
// B unit index: buf*512 + (col>>4)*64 + kgl*16 + (col&15)
__global__ __launch_bounds__(256, 1) void k_fused(
    const float* __restrict__ xr, const float* __restrict__ xi,
    const u16* __restrict__ bt, const float* __restrict__ cfp,
    const float* __restrict__ lw, const float* __restrict__ lb,
    float* __restrict__ outR, float* __restrict__ outI) {
  __shared__ __align__(16) u16 A_lds[32 * 256 * 8];  // 128 KB: 32 kk-chunks x 256 units
  __shared__ __align__(16) u16 B_lds[2 * 512 * 8];   // 16 KB: 2 bufs x 512 units
  __shared__ float scale_lds[R];

  const int tid = threadIdx.x;
  const int lane = tid & 63;
  const int l15 = lane & 15, l4 = lane >> 4;
  const int wid = tid >> 6;              // 4 waves
  const int wr = wid >> 1, wc = wid & 1; // 2x2 wave grid, wave tile 32x64
  const size_t row0 = (size_t)blockIdx.x * R;
  const float cf = cfp[0];

  // ---- phase 0: stage A (f32 -> bf16, fragment-major) + per-row coherence ----
  {
    int row = tid >> 2;  // 0..63
    int s8 = tid & 3;    // 4 threads per row
    const float* xrp = xr + (row0 + row) * D;
    const float* xip = xi + (row0 + row) * D;
    float sc = 0.f, ss = 0.f;
    for (int step = 0; step < 32; ++step) {
      int p = s8 + step * 4;  // k-pair 0..127 (8 floats each)
      f32x4 a0 = *(const f32x4*)(xrp + p * 8);
      f32x4 a1 = *(const f32x4*)(xrp + p * 8 + 4);
      f32x4 b0 = *(const f32x4*)(xip + p * 8);
      f32x4 b1 = *(const f32x4*)(xip + p * 8 + 4);
      float fx[8] = {a0.x, a0.y, a0.z, a0.w, a1.x, a1.y, a1.z, a1.w};
      float fy[8] = {b0.x, b0.y, b0.z, b0.w, b1.x, b1.y, b1.z, b1.w};
      s16x8 v;
#pragma unroll
      for (int j = 0; j < 8; ++j) {
        float x = fx[j] + EPS, y = fy[j] + EPS;
        float inv = rsqrtf(x * x + y * y);
        sc += x * inv;
        ss += y * inv;
        v[j] = (short)f2bf(fx[j]);
      }
      int u = (p >> 2) * 256 + (row >> 4) * 64 + (p & 3) * 16 + (row & 15);
      *(s16x8*)&A_lds[u * 8] = v;
    }
    sc += __shfl_xor(sc, 1, 64); sc += __shfl_xor(sc, 2, 64);
    ss += __shfl_xor(ss, 1, 64); ss += __shfl_xor(ss, 2, 64);
    if (s8 == 0) {
      float coh = (sc * sc + ss * ss) * (1.0f / (1024.0f * 1024.0f));
      scale_lds[row] = cf * (1.0f - coh);
    }
  }
  __syncthreads();

  // ---- GEMM: flat loop over 256 steps (tn = s>>5, kk = s&31), dbuf B ----
  f32x4 acc[2][4] = {};

  // stage helper: fill B_lds[buf] for step s (2 units/thread, b128 in/out)
  auto stage = [&](int buf, int s) {
    int tn = s >> 5, kk = s & 31;
    int cl = tid >> 1;  // local col 0..127
#pragma unroll
    for (int j = 0; j < 2; ++j) {
      int pl = (tid & 1) * 2 + j;  // k-group 0..3
      s16x8 v = *(const s16x8*)(bt + (size_t)(tn * 128 + cl) * D + kk * 32 + pl * 8);
      int u = buf * 512 + (cl >> 4) * 64 + pl * 16 + (cl & 15);
      *(s16x8*)&B_lds[u * 8] = v;
    }
  };

  stage(0, 0);
  __syncthreads();

  for (int s_ = 0; s_ < 256; ++s_) {
    if (s_ + 1 < 256) stage((s_ + 1) & 1, s_ + 1);

    {  // compute step s_
      int kk = s_ & 31, buf = s_ & 1;
      bf16x8 af[2], bf[4];
#pragma unroll
      for (int mf = 0; mf < 2; ++mf) {
        int u = kk * 256 + (wr * 2 + mf) * 64 + l4 * 16 + l15;
        af[mf] = __builtin_bit_cast(bf16x8, *(const s16x8*)&A_lds[u * 8]);
      }
#pragma unroll
      for (int nf = 0; nf < 4; ++nf) {
        int u = buf * 512 + (wc * 4 + nf) * 64 + l4 * 16 + l15;
        bf[nf] = __builtin_bit_cast(bf16x8, *(const s16x8*)&B_lds[u * 8]);
      }
#pragma unroll
      for (int mf = 0; mf < 2; ++mf)
#pragma unroll
        for (int nf = 0; nf < 4; ++nf)
          acc[mf][nf] = __builtin_amdgcn_mfma_f32_16x16x32_bf16(af[mf], bf[nf], acc[mf][nf], 0, 0, 0);
    }

    if ((s_ & 31) == 31) {  // epilogue for tn = s_>>5: rotate + normalize + store
      int tn = s_ >> 5;
#pragma unroll
      for (int mf = 0; mf < 2; ++mf) {
#pragma unroll
        for (int i = 0; i < 4; ++i) {
          int row_l = wr * 32 + mf * 16 + l4 * 4 + i;
          float scl = scale_lds[row_l];
          const float* xrp = xr + (row0 + row_l) * D;
          const float* xip = xi + (row0 + row_l) * D;
          float* orp = outR + (row0 + row_l) * D;
          float* oip = outI + (row0 + row_l) * D;
#pragma unroll
          for (int nf = 0; nf < 4; ++nf) {
            int gcol = tn * 128 + wc * 64 + nf * 16 + l15;
            float t = acc[mf][nf][i] * scl;
            float sn, cs;
            __sincosf(t, &sn, &cs);
            float a = xrp[gcol], b = xip[gcol];
            float nr = a * cs - b * sn;
            float ni = a * sn + b * cs;
            float inv = rsqrtf(nr * nr + ni * ni + EPS);
            orp[gcol] = nr * inv;
            oip[gcol] = ni * inv;
          }
        }
      }
#pragma unroll
      for (int mf = 0; mf < 2; ++mf)
#pragma unroll
        for (int nf = 0; nf < 4; ++nf)
          acc[mf][nf] = f32x4{0.f, 0.f, 0.f, 0.f};
    }
    __syncthreads();
  }

  // ---- phase 2: LayerNorm over this block's 128 output rows (L2-hot) ----
  for (int rr = wid; rr < 2 * R; rr += 4) {
    float* base = (rr < R) ? (outR + (row0 + rr) * D) : (outI + (row0 + rr - R) * D);
    f32x4 v[4];
    float sum = 0.f, sq = 0.f;
#pragma unroll
    for (int c = 0; c < 4; ++c) {
      v[c] = ((const f32x4*)base)[c * 64 + lane];
#pragma unroll
      for (int j = 0; j < 4; ++j) { sum += v[c][j]; sq += v[c][j] * v[c][j]; }
    }
#pragma unroll
    for (int off = 1; off < 64; off <<= 1) {
      sum += __shfl_xor(sum, off, 64);
      sq += __shfl_xor(sq, off, 64);
    }
    float mu = sum * (1.0f / D);
    float rsd = rsqrtf(sq * (1.0f / D) - mu * mu + EPS);
#pragma unroll
    for (int c = 0; c < 4; ++c) {
      f32x4 w4 = ((const f32x4*)lw)[c * 64 + lane];
      f32x4 b4 = ((const f32x4*)lb)[c * 64 + lane];
      f32x4 o;
#pragma unroll
      for (int j = 0; j < 4; ++j) o[j] = (v[c][j] - mu) * rsd * w4[j] + b4[j];
      ((f32x4*)base)[c * 64 + lane] = o;
    }
  }
}

extern "C" void kernel_launch(void* const* d_in, const int* in_sizes, int n_in,
                              void* d_out, int out_size, void* d_ws, size_t ws_size,
                              hipStream_t stream) {
  const float* xr = (const float*)d_in[0];
  const float* xi = (const float*)d_in[1];
  const float* pm = (const float*)d_in[2];
  const float* cf = (const float*)d_in[3];
  const float* lw = (const float*)d_in[4];
  const float* lb = (const float*)d_in[5];
  float* outR = (float*)d_out;
  float* outI = outR + (size_t)M * D;
  u16* bt = (u16*)d_ws;  // 2 MB bf16 B^T

  k_transpose<<<dim3(32, 32), dim3(32, 8), 0, stream>>>(pm, bt);
  k_fused<<<M / R, 256, 0, stream>>>(xr, xi, bt, cf, lw, lb, outR, outI);
}